// Round 14
// baseline (87.696 us; speedup 1.0000x reference)
//
#include <hip/hip_runtime.h>
#include <math.h>

// Problem constants (from reference)
#define NX 128
#define NY 128
#define NZ 64
#define NVOX (NX * NY * NZ)   // 1048576 = 1<<20
#define NC 32
#define FH 120
#define FW 160
#define FHW (FH * FW)         // 19200
#define VOXSZ 0.04f
#define NB 2

// Pinned f32 pipeline, PAIRWISE einsum association (4-accumulator microkernel
// / tree-reduce order):
//   c = (p0 + p1) + (p2 + p3),  p_j individually-rounded f32 products
// world coords: separate rounded ops wx = fl(fl(i*0.04f) + ox)  (R2-style)
// division: IEEE f32 (verified correctly-rounded on gfx950, R10 == R2)
// rounding: __float2int_rn (half-even = np.round)
__global__ __launch_bounds__(256) void voxel_backproject_kernel(
    const float* __restrict__ proj,    // (B,3,4)
    const float* __restrict__ feat,    // (B,C,H,W)
    const float* __restrict__ origin,  // (B,3)
    float* __restrict__ out)
{
#pragma clang fp contract(off)
    const int per_b = NVOX / 4;                       // 262144 threads per batch
    const int tid = blockIdx.x * blockDim.x + threadIdx.x;
    const int b  = tid / per_b;
    const int v4 = tid - b * per_b;
    const int n0 = v4 * 4;                            // first voxel id
    const int i  = n0 >> 13;                          // n0 / (NY*NZ)
    const int j  = (n0 >> 6) & (NY - 1);
    const int k0 = n0 & (NZ - 1);

    const float* P = proj + b * 12;
    const float ox = origin[b * 3 + 0];
    const float oy = origin[b * 3 + 1];
    const float oz = origin[b * 3 + 2];

    // world coords: separate rounded f32 ops
    const float wx = (float)i * VOXSZ + ox;
    const float wy = (float)j * VOXSZ + oy;

    // pairwise left half: (p0 + p1)
    const float tx = P[0] * wx + P[1] * wy;
    const float ty = P[4] * wx + P[5] * wy;
    const float tz = P[8] * wx + P[9] * wy;

    int   idx[4];
    bool  vld[4];
    float4 vmask;
    float* vmp = &vmask.x;

    #pragma unroll
    for (int q = 0; q < 4; ++q) {
        const float wz = (float)(k0 + q) * VOXSZ + oz;
        // pairwise right half then outer add: (p0+p1) + (p2+p3)
        const float cx = tx + (P[2]  * wz + P[3]);
        const float cy = ty + (P[6]  * wz + P[7]);
        const float cz = tz + (P[10] * wz + P[11]);
        const float qx = cx / cz;                     // IEEE f32 divide
        const float qy = cy / cz;
        const int px = __float2int_rn(qx);            // round half-to-even
        const int py = __float2int_rn(qy);
        const bool v = (px >= 0) & (py >= 0) & (px < FW) & (py < FH) & (cz > 0.0f);
        const int pxc = min(max(px, 0), FW - 1);
        const int pyc = min(max(py, 0), FH - 1);
        idx[q] = pyc * FW + pxc;
        vld[q] = v;
        vmp[q] = v ? 1.0f : 0.0f;
    }

    // valid output: offset B*C*NVOX + b*NVOX + n0
    float* vout = out + (size_t)NB * NC * NVOX + (size_t)b * NVOX + n0;
    *reinterpret_cast<float4*>(vout) = vmask;

    const float* fb = feat + (size_t)b * NC * FHW;
    float* ob = out + (size_t)b * NC * NVOX + n0;

    #pragma unroll 4
    for (int c = 0; c < NC; ++c) {
        const float* fc = fb + (size_t)c * FHW;
        float4 o;
        o.x = vld[0] ? fc[idx[0]] : 0.0f;
        o.y = vld[1] ? fc[idx[1]] : 0.0f;
        o.z = vld[2] ? fc[idx[2]] : 0.0f;
        o.w = vld[3] ? fc[idx[3]] : 0.0f;
        *reinterpret_cast<float4*>(ob + (size_t)c * NVOX) = o;
    }
}

extern "C" void kernel_launch(void* const* d_in, const int* in_sizes, int n_in,
                              void* d_out, int out_size, void* d_ws, size_t ws_size,
                              hipStream_t stream) {
    const float* proj   = (const float*)d_in[0];
    const float* feat   = (const float*)d_in[1];
    const float* origin = (const float*)d_in[2];
    float* out = (float*)d_out;

    const int total_threads = NB * (NVOX / 4);        // 524288
    const int block = 256;
    const int grid = total_threads / block;           // 2048
    voxel_backproject_kernel<<<grid, block, 0, stream>>>(proj, feat, origin, out);
}

// Round 15
// 71.194 us; speedup vs baseline: 1.2318x; 1.2318x over previous
//
#include <hip/hip_runtime.h>
#include <math.h>

#define NX 128
#define NY 128
#define NZ 64
#define NVOX (NX * NY * NZ)   // 1048576 = 1<<20
#define NC 32
#define FH 120
#define FW 160
#define FHW (FH * FW)         // 19200
#define VOXSZ 0.04f
#define NB 2
#define T_BYTES ((size_t)NB * FHW * NC * 4)   // 4,915,200

// Transpose features (B,C,H*W) -> T (B, H*W, C): one thread per (b,pix).
// Loads coalesced per-channel; row write is 128B contiguous per thread.
__global__ __launch_bounds__(256) void transpose_feat_kernel(
    const float* __restrict__ feat, float* __restrict__ T)
{
    const int t = blockIdx.x * 256 + threadIdx.x;     // 0..38399
    const int b = t / FHW;
    const int pix = t - b * FHW;
    const float* fb = feat + (size_t)b * NC * FHW + pix;
    float v[NC];
    #pragma unroll
    for (int c = 0; c < NC; ++c) v[c] = fb[(size_t)c * FHW];
    float4* row = (float4*)(T + ((size_t)b * FHW + pix) * NC);
    #pragma unroll
    for (int r = 0; r < NC / 4; ++r)
        row[r] = make_float4(v[4*r], v[4*r+1], v[4*r+2], v[4*r+3]);
}

// One thread per voxel. Projection pipeline is the PINNED R14 pipeline
// (bit-exact vs harness ref): f32, contract off, pairwise association
//   c = (P0*wx + P1*wy) + (P2*wz + P3)
// IEEE f32 divide, __float2int_rn (half-even).
// TR=true: gather 32 channels as 8xfloat4 from transposed T; TR=false:
// fallback, 32 scalar gathers from feat (same values bit-exactly).
template <bool TR>
__global__ __launch_bounds__(256) void voxel_backproject_kernel(
    const float* __restrict__ proj,
    const float* __restrict__ src,     // T if TR else feat
    const float* __restrict__ origin,
    float* __restrict__ out)
{
#pragma clang fp contract(off)
    const int tid = blockIdx.x * 256 + threadIdx.x;
    const int b = tid >> 20;
    const int n = tid & (NVOX - 1);
    const int i = n >> 13;
    const int j = (n >> 6) & (NY - 1);
    const int k = n & (NZ - 1);

    const float* P = proj + b * 12;
    const float ox = origin[b * 3 + 0];
    const float oy = origin[b * 3 + 1];
    const float oz = origin[b * 3 + 2];

    const float wx = (float)i * VOXSZ + ox;
    const float wy = (float)j * VOXSZ + oy;
    const float wz = (float)k * VOXSZ + oz;

    const float tx = P[0] * wx + P[1] * wy;
    const float ty = P[4] * wx + P[5] * wy;
    const float tz = P[8] * wx + P[9] * wy;

    const float cx = tx + (P[2]  * wz + P[3]);
    const float cy = ty + (P[6]  * wz + P[7]);
    const float cz = tz + (P[10] * wz + P[11]);

    const float qx = cx / cz;
    const float qy = cy / cz;
    const int px = __float2int_rn(qx);
    const int py = __float2int_rn(qy);
    const bool v = (px >= 0) & (py >= 0) & (px < FW) & (py < FH) & (cz > 0.0f);

    float4 r0 = {0,0,0,0}, r1 = {0,0,0,0}, r2 = {0,0,0,0}, r3 = {0,0,0,0};
    float4 r4 = {0,0,0,0}, r5 = {0,0,0,0}, r6 = {0,0,0,0}, r7 = {0,0,0,0};
    if (v) {
        const int idx = py * FW + px;
        if (TR) {
            const float4* row = (const float4*)(src + ((size_t)b * FHW + idx) * NC);
            r0 = row[0]; r1 = row[1]; r2 = row[2]; r3 = row[3];
            r4 = row[4]; r5 = row[5]; r6 = row[6]; r7 = row[7];
        } else {
            const float* fb = src + (size_t)b * NC * FHW + idx;
            float t[NC];
            #pragma unroll
            for (int c = 0; c < NC; ++c) t[c] = fb[(size_t)c * FHW];
            r0 = make_float4(t[0],t[1],t[2],t[3]);    r1 = make_float4(t[4],t[5],t[6],t[7]);
            r2 = make_float4(t[8],t[9],t[10],t[11]);  r3 = make_float4(t[12],t[13],t[14],t[15]);
            r4 = make_float4(t[16],t[17],t[18],t[19]);r5 = make_float4(t[20],t[21],t[22],t[23]);
            r6 = make_float4(t[24],t[25],t[26],t[27]);r7 = make_float4(t[28],t[29],t[30],t[31]);
        }
    }

    float* ob = out + (size_t)b * NC * NVOX + n;
    const float4 rr[8] = {r0,r1,r2,r3,r4,r5,r6,r7};
    #pragma unroll
    for (int t = 0; t < 8; ++t) {
        __builtin_nontemporal_store(rr[t].x, ob + (size_t)(4*t + 0) * NVOX);
        __builtin_nontemporal_store(rr[t].y, ob + (size_t)(4*t + 1) * NVOX);
        __builtin_nontemporal_store(rr[t].z, ob + (size_t)(4*t + 2) * NVOX);
        __builtin_nontemporal_store(rr[t].w, ob + (size_t)(4*t + 3) * NVOX);
    }
    float* vout = out + (size_t)NB * NC * NVOX + (size_t)b * NVOX + n;
    __builtin_nontemporal_store(v ? 1.0f : 0.0f, vout);
}

extern "C" void kernel_launch(void* const* d_in, const int* in_sizes, int n_in,
                              void* d_out, int out_size, void* d_ws, size_t ws_size,
                              hipStream_t stream) {
    const float* proj   = (const float*)d_in[0];
    const float* feat   = (const float*)d_in[1];
    const float* origin = (const float*)d_in[2];
    float* out = (float*)d_out;

    const int total = NB * NVOX;                      // 2097152
    const int grid = total / 256;                     // 8192
    if (ws_size >= T_BYTES) {
        float* T = (float*)d_ws;
        transpose_feat_kernel<<<(NB * FHW) / 256, 256, 0, stream>>>(feat, T);
        voxel_backproject_kernel<true><<<grid, 256, 0, stream>>>(proj, T, origin, out);
    } else {
        voxel_backproject_kernel<false><<<grid, 256, 0, stream>>>(proj, feat, origin, out);
    }
}